// Round 9
// baseline (40.402 us; speedup 1.0000x reference)
//
#include <hip/hip_runtime.h>
#include <math.h>

#define N 64
#define PLANE 4096
#define FBIG 3.4e38f
#define MASK1 0x17u              // labels {0,1,2,4} (pair 1)
#define MASK2 0x13u              // labels {0,1,4}   (pair 2)
#define LP 68                    // u32 LDS row stride (16B-aligned rows)
typedef unsigned long long ull;
typedef __attribute__((ext_vector_type(4))) unsigned int u32x4;

// ---------------------------------------------------------------------------
// Workspace (bytes):
//   CX_OFF: ull cx[4][4096]   — y-column occupancy masks, mi = m*2+b
//   ML_OFF: ull mL[4][4096]   — levelzero zero-set  (cx | dilate(cx))
//   BD_OFF: ull bnd[4][4096]  — boundary bits       (dilate(cx) & ~cx)
//   PART_OFF: float part[256][8]; CTR_OFF: int ctr (memset 0 each call)
// edt_all block bid: mi=bid>>6 (m=bid>>7, b=(bid>>6)&1), y0=bid&63.
//   m=0: tsd1 x bnd2 -> h_outer; m=1: tsd2 x bnd1 -> h_inner.
// ---------------------------------------------------------------------------
#define CX_OFF ((size_t)0)
#define ML_OFF ((size_t)131072)
#define BD_OFF ((size_t)262144)
#define PART_OFF ((size_t)393216)
#define CTR_OFF (PART_OFF + (size_t)256 * 8 * 4)

// K1: binarize mmap -> y-column bitmasks for both label masks.
__global__ __launch_bounds__(512) void build_bits(const int* __restrict__ mmap,
                                                  void* __restrict__ wsv) {
  __shared__ unsigned char colb[2][8][64];
  const int bid = blockIdx.x;       // b*64 + x
  const int b = bid >> 6, x = bid & 63;
  const int t = threadIdx.x;
  const int z = t & 63, c = t >> 6;
  const size_t pb = (size_t)(b * N + x) * PLANE;
  unsigned b1 = 0, b2 = 0;
  #pragma unroll
  for (int k = 0; k < 8; ++k) {
    const int v = mmap[pb + (8 * c + k) * N + z];
    b1 |= ((MASK1 >> v) & 1u) << k;
    b2 |= ((MASK2 >> v) & 1u) << k;
  }
  colb[0][c][z] = (unsigned char)b1;
  colb[1][c][z] = (unsigned char)b2;
  __syncthreads();
  if (t < 128) {
    const int mm = t >> 6, zz = t & 63;
    ull v = 0;
    #pragma unroll
    for (int cc = 0; cc < 8; ++cc)
      v |= (ull)colb[mm][cc][zz] << (8 * cc);
    ((ull*)((char*)wsv + CX_OFF))[(size_t)(mm * 2 + b) * 4096 + x * 64 + zz] = v;
  }
}

// K2: 6-neighbor dilation stencil on the bit-volumes (runs ONCE per (m,b)).
__global__ __launch_bounds__(512) void stencil_k(void* __restrict__ wsv) {
  const int idx = blockIdx.x * 512 + threadIdx.x;  // [0, 16384)
  const int mi = idx >> 12, ci = idx & 4095;
  const int x = ci >> 6, z = ci & 63;
  const ull* cx = (const ull*)((char*)wsv + CX_OFF) + (size_t)mi * 4096;
  const ull c0 = cx[ci];
  const ull xm = (x > 0) ? cx[ci - 64] : 0ull;
  const ull xp = (x < 63) ? cx[ci + 64] : 0ull;
  const ull zm = (z > 0) ? cx[ci - 1] : 0ull;
  const ull zp = (z < 63) ? cx[ci + 1] : 0ull;
  const ull nb = xm | xp | zm | zp | (c0 << 1) | (c0 >> 1);
  ((ull*)((char*)wsv + ML_OFF))[(size_t)mi * 4096 + ci] = c0 | nb;
  ((ull*)((char*)wsv + BD_OFF))[(size_t)mi * 4096 + ci] = nb & ~c0;
}

// K3: one block per (m,b,y0); Y-eval at y0 + Z-env + X-env all in LDS.
__global__ __launch_bounds__(1024) void edt_all(void* __restrict__ wsv,
                                                float* __restrict__ out) {
  __shared__ unsigned int g1p[64][LP];   // [x][z] packed u16 lo=T hi=L (+z^2)
  __shared__ unsigned int g2p[64][LP];   // [z][x] packed u16 (+z'^2 +x^2)
  __shared__ float redS[16], redB[16], redM[16];
  __shared__ int lastFlag;
  const int bid = blockIdx.x;            // (m*2+b)*64 + y0
  const int m = bid >> 7;
  const int mi = bid >> 6;               // m*2+b
  const int y0 = bid & 63;
  const int t = threadIdx.x;

  const ull* cxO = (const ull*)((char*)wsv + CX_OFF) + (size_t)mi * 4096;
  const ull* mLO = (const ull*)((char*)wsv + ML_OFF) + (size_t)mi * 4096;
  const ull* bndP = (const ull*)((char*)wsv + BD_OFF) +
                    (size_t)((1 - m) * 2 + (mi & 1)) * 4096;

  // ---- phase A: Y-distances at y0 for tdm (mT=~cx) and levelzero (mL) ----
  #pragma unroll
  for (int k = 0; k < 4; ++k) {
    const int ci = t + 1024 * k;
    const int x = ci >> 6, z = ci & 63;
    const ull mT = ~cxO[ci];
    const ull mLw = mLO[ci];
    const int zs = z * z;
    unsigned vT, vL;
    {
      const ull hi = mT >> y0;
      const int du = hi ? (__ffsll((long long)hi) - 1) : 99;
      const int dd = (int)__clzll((long long)(mT << (63 - y0)));  // 64 if none
      const int d = min(du, dd);
      vT = (d > 63) ? 65535u : (unsigned)(d * d + zs);
    }
    {
      const ull hi = mLw >> y0;
      const int du = hi ? (__ffsll((long long)hi) - 1) : 99;
      const int dd = (int)__clzll((long long)(mLw << (63 - y0)));
      const int d = min(du, dd);
      vL = (d > 63) ? 65535u : (unsigned)(d * d + zs);
    }
    g1p[x][z] = vT | (vL << 16);
  }
  __syncthreads();

  // ---- phase B: Z-envelope. Thread x=t>>4, outputs z'=g+16q (q<4). ----
  {
    const int x = t >> 4, g = t & 15;
    const u32x4* row4 = (const u32x4*)&g1p[x][0];
    float aT[4], aL[4], zq[4];
    #pragma unroll
    for (int q = 0; q < 4; ++q) {
      aT[q] = FBIG; aL[q] = FBIG; zq[q] = (float)(g + 16 * q);
    }
    float m2j = 0.f;
    #pragma unroll 4
    for (int j4 = 0; j4 < 16; ++j4) {
      const u32x4 v4 = row4[j4];
      #pragma unroll
      for (int e = 0; e < 4; ++e) {
        const unsigned v = v4[e];
        const float fT = (float)(v & 0xffffu);
        const float fL = (float)(v >> 16);
        #pragma unroll
        for (int q = 0; q < 4; ++q) {
          aT[q] = fminf(aT[q], fmaf(m2j, zq[q], fT));
          aL[q] = fminf(aL[q], fmaf(m2j, zq[q], fL));
        }
        m2j -= 2.f;
      }
    }
    const float xs = (float)(x * x);
    #pragma unroll
    for (int q = 0; q < 4; ++q) {
      const int zi = g + 16 * q;
      const float vT = fminf(fmaf(zq[q], zq[q], aT[q]) + xs, 65535.f);
      const float vL = fminf(fmaf(zq[q], zq[q], aL[q]) + xs, 65535.f);
      g2p[zi][x] = (unsigned)vT | ((unsigned)vL << 16);  // transposed store
    }
  }
  __syncthreads();

  // ---- phase C: X-envelope + epilogue. Thread z=t>>4, outputs x'=g+16q. ----
  {
    const int z = t >> 4, g = t & 15;
    const u32x4* row4 = (const u32x4*)&g2p[z][0];
    float aT[4], aL[4], xq[4];
    #pragma unroll
    for (int q = 0; q < 4; ++q) {
      aT[q] = FBIG; aL[q] = FBIG; xq[q] = (float)(g + 16 * q);
    }
    float m2j = 0.f;
    #pragma unroll 4
    for (int j4 = 0; j4 < 16; ++j4) {
      const u32x4 v4 = row4[j4];
      #pragma unroll
      for (int e = 0; e < 4; ++e) {
        const unsigned v = v4[e];
        const float fT = (float)(v & 0xffffu);
        const float fL = (float)(v >> 16);
        #pragma unroll
        for (int q = 0; q < 4; ++q) {
          aT[q] = fminf(aT[q], fmaf(m2j, xq[q], fT));
          aL[q] = fminf(aL[q], fmaf(m2j, xq[q], fL));
        }
        m2j -= 2.f;
      }
    }
    float hsum = 0.f, bsum = 0.f, hmax = 0.f;
    #pragma unroll
    for (int q = 0; q < 4; ++q) {
      const int x = g + 16 * q;
      const float eT = fmaf(xq[q], xq[q], aT[q]);
      const float eL = fmaf(xq[q], xq[q], aL[q]);
      const float tsd = sqrtf(eT) - sqrtf(eL);
      const float bnd = (float)((bndP[x * 64 + z] >> y0) & 1ull);
      const float h = bnd * fabsf(tsd);
      hsum += h; bsum += bnd; hmax = fmaxf(hmax, h);
    }
    #pragma unroll
    for (int o = 32; o > 0; o >>= 1) {
      hsum += __shfl_down(hsum, o);
      bsum += __shfl_down(bsum, o);
      hmax = fmaxf(hmax, __shfl_down(hmax, o));
    }
    const int w = t >> 6;
    if ((t & 63) == 0) { redS[w] = hsum; redB[w] = bsum; redM[w] = hmax; }
  }
  __syncthreads();

  float* part = (float*)((char*)wsv + PART_OFF);
  int* ctr = (int*)((char*)wsv + CTR_OFF);
  if (t == 0) {
    float s = 0.f, bs = 0.f, mx = 0.f;
    #pragma unroll
    for (int i = 0; i < 16; ++i) {
      s += redS[i]; bs += redB[i]; mx = fmaxf(mx, redM[i]);
    }
    float* p = part + (size_t)bid * 8;
    p[0] = s; p[1] = bs; p[2] = mx;
    __threadfence();
    const int old = atomicAdd(ctr, 1);
    lastFlag = (old == 255) ? 1 : 0;
  }
  __syncthreads();
  if (lastFlag) {
    __threadfence();  // acquire other blocks' partials
    float s = 0.f, bs = 0.f, mx = 0.f;
    if (t < 256) {
      const float* p = part + (size_t)t * 8;
      s = p[0]; bs = p[1]; mx = p[2];
    }
    #pragma unroll
    for (int o = 32; o > 0; o >>= 1) {
      s += __shfl_down(s, o);
      bs += __shfl_down(bs, o);
      mx = fmaxf(mx, __shfl_down(mx, o));
    }
    __syncthreads();
    if ((t & 63) == 0 && t < 256) {
      redS[t >> 6] = s; redB[t >> 6] = bs; redM[t >> 6] = mx;
    }
    __syncthreads();
    if (t == 0) {
      // partials p<128 are m=0: h_outer + bnd2; p>=128: h_inner + bnd1
      const float s_ho = redS[0] + redS[1], b2 = redB[0] + redB[1];
      const float mho = fmaxf(redM[0], redM[1]);
      const float s_hi = redS[2] + redS[3], b1 = redB[2] + redB[3];
      const float mhi = fmaxf(redM[2], redM[3]);
      const float him = s_hi / b1;
      const float hom = s_ho / b2;
      out[0] = him;
      out[1] = mhi;
      out[2] = hom;
      out[3] = mho;
      out[4] = (him - 2.f) * (him - 2.f) + (hom - 2.f) * (hom - 2.f);
    }
  }
}

extern "C" void kernel_launch(void* const* d_in, const int* in_sizes, int n_in,
                              void* d_out, int out_size, void* d_ws,
                              size_t ws_size, hipStream_t stream) {
  (void)in_sizes; (void)n_in; (void)out_size; (void)ws_size;
  const int* mmap = (const int*)d_in[0];
  float* out = (float*)d_out;

  hipMemsetAsync((char*)d_ws + CTR_OFF, 0, 8, stream);
  build_bits<<<128, 512, 0, stream>>>(mmap, d_ws);
  stencil_k<<<32, 512, 0, stream>>>(d_ws);
  edt_all<<<256, 1024, 0, stream>>>(d_ws, out);
}

// Round 10
// 34.029 us; speedup vs baseline: 1.1873x; 1.1873x over previous
//
#include <hip/hip_runtime.h>
#include <math.h>

#define N 64
#define PLANE 4096
#define MASK1 0x17u              // labels {0,1,2,4} (pair 1)
#define MASK2 0x13u              // labels {0,1,4}   (pair 2)
#define SENT 16000               // i16 sentinel: > 7938+62, quasi > 11907 (exactness proof in notes)
typedef unsigned long long ull;

// ---------------------------------------------------------------------------
// Workspace (bytes):
//   CX_OFF: ull cx[4][4096]   — y-column occupancy masks, mi = m*2+b
//   ML_OFF: ull mL[4][4096]   — levelzero zero-set  (cx | dilate(cx))
//   BD_OFF: ull bnd[4][4096]  — boundary bits       (dilate(cx) & ~cx)
//   PART_OFF: float part[256][8]; CTR_OFF: int ctr (zeroed by build_bits)
// edt_all block bid: mi=bid>>6 (m=bid>>7), y0=bid&63.
//   m=0: tsd1 x bnd2 -> h_outer; m=1: tsd2 x bnd1 -> h_inner.
// ---------------------------------------------------------------------------
#define CX_OFF ((size_t)0)
#define ML_OFF ((size_t)131072)
#define BD_OFF ((size_t)262144)
#define PART_OFF ((size_t)393216)
#define CTR_OFF (PART_OFF + (size_t)256 * 8 * 4)

// K1: binarize mmap -> y-column bitmasks; zero the completion counter.
__global__ __launch_bounds__(512) void build_bits(const int* __restrict__ mmap,
                                                  void* __restrict__ wsv) {
  __shared__ unsigned char colb[2][8][64];
  const int bid = blockIdx.x;       // b*64 + x
  const int b = bid >> 6, x = bid & 63;
  const int t = threadIdx.x;
  const int z = t & 63, c = t >> 6;
  if (bid == 0 && t < 2) ((int*)((char*)wsv + CTR_OFF))[t] = 0;
  const size_t pb = (size_t)(b * N + x) * PLANE;
  unsigned b1 = 0, b2 = 0;
  #pragma unroll
  for (int k = 0; k < 8; ++k) {
    const int v = mmap[pb + (8 * c + k) * N + z];
    b1 |= ((MASK1 >> v) & 1u) << k;
    b2 |= ((MASK2 >> v) & 1u) << k;
  }
  colb[0][c][z] = (unsigned char)b1;
  colb[1][c][z] = (unsigned char)b2;
  __syncthreads();
  if (t < 128) {
    const int mm = t >> 6, zz = t & 63;
    ull v = 0;
    #pragma unroll
    for (int cc = 0; cc < 8; ++cc)
      v |= (ull)colb[mm][cc][zz] << (8 * cc);
    ((ull*)((char*)wsv + CX_OFF))[(size_t)(mm * 2 + b) * 4096 + x * 64 + zz] = v;
  }
}

// K2: 6-neighbor dilation stencil on the bit-volumes (once per (m,b)).
__global__ __launch_bounds__(512) void stencil_k(void* __restrict__ wsv) {
  const int idx = blockIdx.x * 512 + threadIdx.x;  // [0, 16384)
  const int mi = idx >> 12, ci = idx & 4095;
  const int x = ci >> 6, z = ci & 63;
  const ull* cx = (const ull*)((char*)wsv + CX_OFF) + (size_t)mi * 4096;
  const ull c0 = cx[ci];
  const ull xm = (x > 0) ? cx[ci - 64] : 0ull;
  const ull xp = (x < 63) ? cx[ci + 64] : 0ull;
  const ull zm = (z > 0) ? cx[ci - 1] : 0ull;
  const ull zp = (z < 63) ? cx[ci + 1] : 0ull;
  const ull nb = xm | xp | zm | zp | (c0 << 1) | (c0 >> 1);
  ((ull*)((char*)wsv + ML_OFF))[(size_t)mi * 4096 + ci] = c0 | nb;
  ((ull*)((char*)wsv + BD_OFF))[(size_t)mi * 4096 + ci] = nb & ~c0;
}

// K3: one block per (m,b,y0); Y-eval + Z-env + X-env, packed-i16 min-plus.
__global__ __launch_bounds__(512) void edt_all(void* __restrict__ wsv,
                                               float* __restrict__ out) {
  __shared__ unsigned int g1p[64][65];   // [x][z]  {i16 T | i16 L<<16}, +z^2
  __shared__ unsigned int g2p[64][67];   // [z'][x] packed, +z'^2 +x^2
  __shared__ float redS[8], redB[8], redM[8];
  __shared__ int lastFlag;
  const int bid = blockIdx.x;            // (m*2+b)*64 + y0
  const int m = bid >> 7;
  const int mi = bid >> 6;               // m*2+b
  const int y0 = bid & 63;
  const int t = threadIdx.x;

  const ull* cxO = (const ull*)((char*)wsv + CX_OFF) + (size_t)mi * 4096;
  const ull* mLO = (const ull*)((char*)wsv + ML_OFF) + (size_t)mi * 4096;
  const ull* bndP = (const ull*)((char*)wsv + BD_OFF) +
                    (size_t)((1 - m) * 2 + (mi & 1)) * 4096;

  // ---- phase A: Y-distances at y0, packed u16 {T,L}, z^2 folded ----
  #pragma unroll
  for (int k = 0; k < 8; ++k) {
    const int ci = t + 512 * k;
    const int z = ci & 63;
    const ull mT = ~cxO[ci];
    const ull mLw = mLO[ci];
    const int zs = z * z;
    unsigned vT, vL;
    {
      const ull hi = mT >> y0;
      const int du = hi ? (__ffsll((long long)hi) - 1) : 99;
      const int dd = (int)__clzll((long long)(mT << (63 - y0)));  // 64 if none
      const int d = min(du, dd);
      vT = (d > 63) ? (unsigned)SENT : (unsigned)(d * d + zs);
    }
    {
      const ull hi = mLw >> y0;
      const int du = hi ? (__ffsll((long long)hi) - 1) : 99;
      const int dd = (int)__clzll((long long)(mLw << (63 - y0)));
      const int d = min(du, dd);
      vL = (d > 63) ? (unsigned)SENT : (unsigned)(d * d + zs);
    }
    g1p[ci >> 6][z] = vT | (vL << 16);
  }
  __syncthreads();

  // ---- phase B: Z-envelope, packed i16. x=t>>3, outputs z'=g+8q. ----
  {
    const int x = t >> 3, g = t & 7;
    unsigned acc[8], n2i[8];
    #pragma unroll
    for (int q = 0; q < 8; ++q) {
      acc[q] = 0x7FFF7FFFu;
      n2i[q] = (unsigned)(unsigned short)(-2 * (g + 8 * q)) * 0x10001u;
    }
    unsigned jp = 0;  // packed {j, j}
    const unsigned* row = &g1p[x][0];
    #pragma unroll 4
    for (int j = 0; j < 64; ++j) {
      const unsigned fj = row[j];
      #pragma unroll
      for (int q = 0; q < 8; ++q) {
        unsigned d;
        asm("v_pk_mad_i16 %0, %1, %2, %3"
            : "=v"(d) : "v"(n2i[q]), "v"(jp), "v"(fj));
        asm("v_pk_min_i16 %0, %1, %2"
            : "=v"(acc[q]) : "v"(acc[q]), "v"(d));
      }
      jp += 0x10001u;
    }
    const int xs = x * x;
    #pragma unroll
    for (int q = 0; q < 8; ++q) {
      const int zp = g + 8 * q;
      const unsigned spk = (unsigned)(zp * zp + xs) * 0x10001u;
      unsigned gv;
      asm("v_pk_add_i16 %0, %1, %2" : "=v"(gv) : "v"(acc[q]), "v"(spk));
      g2p[zp][x] = gv;  // transposed store for phase C row reads
    }
  }
  __syncthreads();

  // ---- phase C: X-envelope + epilogue. z=t>>3, outputs x'=g+8q. ----
  {
    const int z = t >> 3, g = t & 7;
    unsigned acc[8], n2i[8];
    #pragma unroll
    for (int q = 0; q < 8; ++q) {
      acc[q] = 0x7FFF7FFFu;
      n2i[q] = (unsigned)(unsigned short)(-2 * (g + 8 * q)) * 0x10001u;
    }
    unsigned jp = 0;
    const unsigned* row = &g2p[z][0];
    #pragma unroll 4
    for (int j = 0; j < 64; ++j) {
      const unsigned fj = row[j];
      #pragma unroll
      for (int q = 0; q < 8; ++q) {
        unsigned d;
        asm("v_pk_mad_i16 %0, %1, %2, %3"
            : "=v"(d) : "v"(n2i[q]), "v"(jp), "v"(fj));
        asm("v_pk_min_i16 %0, %1, %2"
            : "=v"(acc[q]) : "v"(acc[q]), "v"(d));
      }
      jp += 0x10001u;
    }
    float hsum = 0.f, bsum = 0.f, hmax = 0.f;
    #pragma unroll
    for (int q = 0; q < 8; ++q) {
      const int xp = g + 8 * q;
      const int xs2 = xp * xp;
      const int eT = (int)(short)(acc[q] & 0xFFFFu) + xs2;
      const int eL = (int)(short)(acc[q] >> 16) + xs2;
      const float tsd = sqrtf((float)eT) - sqrtf((float)eL);
      const float bnd = (float)((bndP[xp * 64 + z] >> y0) & 1ull);
      const float h = bnd * fabsf(tsd);
      hsum += h; bsum += bnd; hmax = fmaxf(hmax, h);
    }
    #pragma unroll
    for (int o = 32; o > 0; o >>= 1) {
      hsum += __shfl_down(hsum, o);
      bsum += __shfl_down(bsum, o);
      hmax = fmaxf(hmax, __shfl_down(hmax, o));
    }
    const int w = t >> 6;
    if ((t & 63) == 0) { redS[w] = hsum; redB[w] = bsum; redM[w] = hmax; }
  }
  __syncthreads();

  float* part = (float*)((char*)wsv + PART_OFF);
  int* ctr = (int*)((char*)wsv + CTR_OFF);
  if (t == 0) {
    float s = 0.f, bs = 0.f, mx = 0.f;
    #pragma unroll
    for (int i = 0; i < 8; ++i) {
      s += redS[i]; bs += redB[i]; mx = fmaxf(mx, redM[i]);
    }
    float* p = part + (size_t)bid * 8;
    p[0] = s; p[1] = bs; p[2] = mx;
    __threadfence();
    const int old = atomicAdd(ctr, 1);
    lastFlag = (old == 255) ? 1 : 0;
  }
  __syncthreads();
  if (lastFlag) {
    __threadfence();  // acquire other blocks' partials
    float s = 0.f, bs = 0.f, mx = 0.f;
    if (t < 256) {
      const float* p = part + (size_t)t * 8;
      s = p[0]; bs = p[1]; mx = p[2];
    }
    #pragma unroll
    for (int o = 32; o > 0; o >>= 1) {
      s += __shfl_down(s, o);
      bs += __shfl_down(bs, o);
      mx = fmaxf(mx, __shfl_down(mx, o));
    }
    __syncthreads();
    if ((t & 63) == 0 && t < 256) {
      redS[t >> 6] = s; redB[t >> 6] = bs; redM[t >> 6] = mx;
    }
    __syncthreads();
    if (t == 0) {
      // partials p<128 are m=0: h_outer + bnd2; p>=128: h_inner + bnd1
      const float s_ho = redS[0] + redS[1], b2 = redB[0] + redB[1];
      const float mho = fmaxf(redM[0], redM[1]);
      const float s_hi = redS[2] + redS[3], b1 = redB[2] + redB[3];
      const float mhi = fmaxf(redM[2], redM[3]);
      const float him = s_hi / b1;
      const float hom = s_ho / b2;
      out[0] = him;
      out[1] = mhi;
      out[2] = hom;
      out[3] = mho;
      out[4] = (him - 2.f) * (him - 2.f) + (hom - 2.f) * (hom - 2.f);
    }
  }
}

extern "C" void kernel_launch(void* const* d_in, const int* in_sizes, int n_in,
                              void* d_out, int out_size, void* d_ws,
                              size_t ws_size, hipStream_t stream) {
  (void)in_sizes; (void)n_in; (void)out_size; (void)ws_size;
  const int* mmap = (const int*)d_in[0];
  float* out = (float*)d_out;

  build_bits<<<128, 512, 0, stream>>>(mmap, d_ws);
  stencil_k<<<32, 512, 0, stream>>>(d_ws);
  edt_all<<<256, 512, 0, stream>>>(d_ws, out);
}